// Round 1
// baseline (348.544 us; speedup 1.0000x reference)
//
#include <hip/hip_runtime.h>

// CIR (Cox-Ingersoll-Ross) Euler-Maruyama scan, full-truncation diffusion.
// B=16384 rows, S=2048 steps, L=64 x-samples per row.
//
// Decomposition: 1 thread per batch row (the scan is sequential in S).
// 16384 threads = 256 waves; block=64 (one wave) x 256 blocks -> ~1 wave/CU.
// Latency hiding is pure ILP: 16-deep float4 register ring prefetch on W.

#define B_ROWS   16384
#define SEQ_LEN  2048
#define L_X      64
#define V_LAST   0.04f
#define DT_CONST (1.0f / 2048.0f)
#define PROB     0.5f

constexpr int DEPTH = 16;              // float4 chunks in flight per thread
constexpr int NCH   = SEQ_LEN / 4;     // 512 float4 chunks per row
constexpr int NGRP  = NCH / DEPTH;     // 32 groups

__device__ __forceinline__ float cir_step(float v, float w, float tol_mu,
                                          float kdt, float sigma) {
    // matches: v + kappa*(tol_mu - v)*DT + sigma*sqrt(max(v*DT,0))*w
    float s     = sqrtf(fmaxf(v * DT_CONST, 0.0f));
    float drift = fmaf(kdt, tol_mu - v, v);   // v + kappa*DT*(tol_mu - v)
    return fmaf(sigma * w, s, drift);
}

__global__ __launch_bounds__(64) void cir_scan_kernel(
    const float* __restrict__ x,      // (B, 64, 1)
    const float* __restrict__ W,      // (B, S)
    const float* __restrict__ kappa_p,
    const float* __restrict__ mu_p,
    const float* __restrict__ sigma_p,
    float* __restrict__ out)          // (B, S, 1) flat
{
    const int row = blockIdx.x * 64 + threadIdx.x;
    if (row >= B_ROWS) return;

    // ---- xmean over 64 samples (256B contiguous per row) ----
    const float4* xr = reinterpret_cast<const float4*>(x + (size_t)row * L_X);
    float sum = 0.0f;
#pragma unroll
    for (int i = 0; i < L_X / 4; ++i) {
        float4 t = xr[i];
        sum += (t.x + t.y) + (t.z + t.w);
    }
    const float xmean = sum * (1.0f / 64.0f);

    const float kappa = kappa_p[0];
    const float mu    = mu_p[0];
    const float sigma = sigma_p[0];

    const float tol_mu     = mu + xmean;
    const float kdt        = kappa * DT_CONST;
    const float half_xmean = (1.0f - PROB) * xmean;

    const float4* Wr = reinterpret_cast<const float4*>(W + (size_t)row * SEQ_LEN);
    float4*       Or = reinterpret_cast<float4*>(out + (size_t)row * SEQ_LEN);

    // ---- prime the prefetch ring ----
    float4 buf[DEPTH];
#pragma unroll
    for (int i = 0; i < DEPTH; ++i) buf[i] = Wr[i];

    float v = V_LAST;

    for (int g = 0; g < NGRP; ++g) {
        const bool more = (g + 1 < NGRP);
        const int  base = g * DEPTH;
#pragma unroll
        for (int i = 0; i < DEPTH; ++i) {
            float4 w4 = buf[i];
            if (more) buf[i] = Wr[base + DEPTH + i];   // prefetch 16 chunks ahead

            float4 o;
            v = cir_step(v, w4.x, tol_mu, kdt, sigma);
            o.x = fmaf(PROB, v, half_xmean);
            v = cir_step(v, w4.y, tol_mu, kdt, sigma);
            o.y = fmaf(PROB, v, half_xmean);
            v = cir_step(v, w4.z, tol_mu, kdt, sigma);
            o.z = fmaf(PROB, v, half_xmean);
            v = cir_step(v, w4.w, tol_mu, kdt, sigma);
            o.w = fmaf(PROB, v, half_xmean);

            Or[base + i] = o;
        }
    }
}

extern "C" void kernel_launch(void* const* d_in, const int* in_sizes, int n_in,
                              void* d_out, int out_size, void* d_ws, size_t ws_size,
                              hipStream_t stream) {
    const float* x     = (const float*)d_in[0];
    const float* W     = (const float*)d_in[1];
    const float* kappa = (const float*)d_in[2];
    const float* mu    = (const float*)d_in[3];
    const float* sigma = (const float*)d_in[4];
    float* out = (float*)d_out;

    dim3 grid(B_ROWS / 64);   // 256 blocks -> ~1 per CU
    dim3 block(64);           // exactly one wave
    hipLaunchKernelGGL(cir_scan_kernel, grid, block, 0, stream,
                       x, W, kappa, mu, sigma, out);
}

// Round 3
// 333.129 us; speedup vs baseline: 1.0463x; 1.0463x over previous
//
#include <hip/hip_runtime.h>

// CIR Euler-Maruyama scan, B=16384 rows x S=2048 steps.
// One wave (64 threads) per block, lane = batch row, grid=256 (~1 wave/CU).
//
// R0 post-mortem: per-lane float4 *stores* caused 2.45x WRITE_SIZE blowup
// (328 MB vs 134 MB ideal) -> write-bound. Reads were fine (L3-absorbed).
// R1's global_load_lds hit a gfx950 backend ICE on the addrspacecast.
//
// This version: keep R0's register-ring read path (per-lane float4, one
// 64-col tile prefetched ahead), but stage each 64x64 result tile in LDS
// (transposed, stride 65 -> all phases <=2 lanes/bank = conflict-free) and
// store coalesced: 64 lanes x 4B = 256B contiguous per instr, full lines.
// Single wave per block -> no __syncthreads; compiler lgkmcnt waits cover
// the within-wave ds_write -> ds_read dependency.

#define B_ROWS   16384
#define SEQ      2048
#define L_X      64
#define V_LAST   0.04f
#define DT_C     (1.0f / 2048.0f)
#define PROB     0.5f

#define TILE     64
#define NT       (SEQ / TILE)     // 32 tiles
#define CHT      (TILE / 4)       // 16 float4 chunks per tile per lane
#define OSTRIDE  65               // o_lds [col][row] pad +1 -> conflict-free

__device__ __forceinline__ float cir_step(float v, float w, float tol_mu,
                                          float kdt, float sigma) {
    // matches: v + kappa*(tol_mu - v)*DT + sigma*sqrt(max(v*DT,0))*w
    float s     = sqrtf(fmaxf(v * DT_C, 0.0f));
    float drift = fmaf(kdt, tol_mu - v, v);
    return fmaf(sigma * w, s, drift);
}

__global__ __launch_bounds__(64) void cir_scan_kernel(
    const float* __restrict__ x,      // (B, 64, 1)
    const float* __restrict__ W,      // (B, S)
    const float* __restrict__ kappa_p,
    const float* __restrict__ mu_p,
    const float* __restrict__ sigma_p,
    float* __restrict__ out)          // (B, S)
{
    __shared__ float o_lds[TILE * OSTRIDE];    // 16.6 KB, layout [col][row]

    const int lane = threadIdx.x;              // 0..63, owns batch row row0+lane
    const int row0 = blockIdx.x * 64;
    const int row  = row0 + lane;

    // ---- xmean over 64 samples (256B contiguous per lane) ----
    const float4* xr = reinterpret_cast<const float4*>(x + (size_t)row * L_X);
    float sum = 0.0f;
#pragma unroll
    for (int i = 0; i < L_X / 4; ++i) {
        float4 t = xr[i];
        sum += (t.x + t.y) + (t.z + t.w);
    }
    const float xmean = sum * (1.0f / 64.0f);

    const float kappa = kappa_p[0];
    const float mu    = mu_p[0];
    const float sigma = sigma_p[0];

    const float tol_mu = mu + xmean;
    const float kdt    = kappa * DT_C;
    const float hx     = (1.0f - PROB) * xmean;

    const float4* Wr = reinterpret_cast<const float4*>(W + (size_t)row * SEQ);

    // ---- prime: tile 0's 16 chunks into the register ring ----
    float4 buf[CHT];
#pragma unroll
    for (int i = 0; i < CHT; ++i) buf[i] = Wr[i];

    float v = V_LAST;

    for (int t = 0; t < NT; ++t) {
        const bool more = (t + 1 < NT);
        const int  nb   = (t + 1) * CHT;

        // ---- compute 64 steps; results -> o_lds transposed ----
#pragma unroll
        for (int i = 0; i < CHT; ++i) {
            float4 w4 = buf[i];
            if (more) buf[i] = Wr[nb + i];     // prefetch next tile's chunk

            const int j = 4 * i;               // col within tile
            v = cir_step(v, w4.x, tol_mu, kdt, sigma);
            o_lds[(j + 0) * OSTRIDE + lane] = fmaf(PROB, v, hx);  // bank (j+lane)%32
            v = cir_step(v, w4.y, tol_mu, kdt, sigma);
            o_lds[(j + 1) * OSTRIDE + lane] = fmaf(PROB, v, hx);
            v = cir_step(v, w4.z, tol_mu, kdt, sigma);
            o_lds[(j + 2) * OSTRIDE + lane] = fmaf(PROB, v, hx);
            v = cir_step(v, w4.w, tol_mu, kdt, sigma);
            o_lds[(j + 3) * OSTRIDE + lane] = fmaf(PROB, v, hx);
        }

        // ---- coalesced store: per row r, 64 lanes write 256B contiguous ----
        const size_t ob = (size_t)row0 * SEQ + (size_t)t * TILE;
#pragma unroll 8
        for (int r = 0; r < 64; ++r) {
            float a = o_lds[lane * OSTRIDE + r];               // bank (lane+r)%32
            out[ob + (size_t)r * SEQ + lane] = a;
        }
    }
}

extern "C" void kernel_launch(void* const* d_in, const int* in_sizes, int n_in,
                              void* d_out, int out_size, void* d_ws, size_t ws_size,
                              hipStream_t stream) {
    const float* x     = (const float*)d_in[0];
    const float* W     = (const float*)d_in[1];
    const float* kappa = (const float*)d_in[2];
    const float* mu    = (const float*)d_in[3];
    const float* sigma = (const float*)d_in[4];
    float* out = (float*)d_out;

    dim3 grid(B_ROWS / 64);   // 256 blocks -> ~1 per CU
    dim3 block(64);           // exactly one wave
    hipLaunchKernelGGL(cir_scan_kernel, grid, block, 0, stream,
                       x, W, kappa, mu, sigma, out);
}